// Round 2
// baseline (1912.535 us; speedup 1.0000x reference)
//
#include <hip/hip_runtime.h>
#include <math.h>

#define TB   720
#define NI   16
#define NH   128
#define NG   512   // 4*H
#define NB   256
#define PRED 96

// decoder: split of W_hh_b row: first WBR cols in regs, last WBL cols in LDS
#define WBR  56
#define WBL  72
#define WST  73    // LDS row stride (odd -> conflict-free)

__device__ __forceinline__ float sigf(float v) { return 1.0f / (1.0f + __expf(-v)); }

// ---------------- encoder ----------------
// grid 256 = (batch-pair) x (dir); block 512; thread t owns gate row t.
// Each WG runs one direction for two batch elements (weights shared in regs).
__global__ __launch_bounds__(512, 1)
void enc_kernel(const float* __restrict__ x,
                const float* __restrict__ Wih_f, const float* __restrict__ Whh_f, const float* __restrict__ b_f,
                const float* __restrict__ Wih_b, const float* __restrict__ Whh_b, const float* __restrict__ b_b,
                float* __restrict__ st)   // st[b][dir][{h,c}][NH]
{
    __shared__ float xs0[TB * NI];
    __shared__ float xs1[TB * NI];
    __shared__ float hs0[NH];
    __shared__ float hs1[NH];
    __shared__ float gs0[NG];
    __shared__ float gs1[NG];

    const int wg  = blockIdx.x;
    const int dir = wg & 1;
    const int pb  = wg >> 1;
    const int b0  = 2 * pb, b1 = 2 * pb + 1;
    const int t   = threadIdx.x;

    const float* Wih = dir ? Wih_b : Wih_f;
    const float* Whh = dir ? Whh_b : Whh_f;
    const float* bv  = dir ? b_b   : b_f;

    // stage both x rows (T*I = 11520 f32 each)
    for (int i = t; i < TB * NI; i += 512) {
        xs0[i] = x[b0 * TB * NI + i];
        xs1[i] = x[b1 * TB * NI + i];
    }

    // weights -> registers
    float wih[NI];
#pragma unroll
    for (int k = 0; k < NI / 4; ++k) {
        float4 v = ((const float4*)(Wih + t * NI))[k];
        wih[4*k] = v.x; wih[4*k+1] = v.y; wih[4*k+2] = v.z; wih[4*k+3] = v.w;
    }
    float whh[NH];
#pragma unroll
    for (int k = 0; k < NH / 4; ++k) {
        float4 v = ((const float4*)(Whh + t * NH))[k];
        whh[4*k] = v.x; whh[4*k+1] = v.y; whh[4*k+2] = v.z; whh[4*k+3] = v.w;
    }
    const float bias = bv[t];

    if (t < NH) { hs0[t] = 0.0f; hs1[t] = 0.0f; }
    float cc = 0.0f;  // t<NH: c of b0 dim t ; NH<=t<2NH: c of b1 dim t-NH
    __syncthreads();

    for (int s = 0; s < TB; ++s) {
        const int tt = dir ? (TB - 1 - s) : s;
        const float* xp0 = &xs0[tt * NI];
        const float* xp1 = &xs1[tt * NI];
        float a0 = bias, a0b = 0.0f;
        float a1 = bias, a1b = 0.0f;
#pragma unroll
        for (int j = 0; j < NI; j += 2) {
            a0  += xp0[j]     * wih[j];
            a0b += xp0[j + 1] * wih[j + 1];
            a1  += xp1[j]     * wih[j];
            a1b += xp1[j + 1] * wih[j + 1];
        }
        const float4* h40 = (const float4*)hs0;
        const float4* h41 = (const float4*)hs1;
#pragma unroll
        for (int k = 0; k < NH / 4; ++k) {
            float4 v0 = h40[k];
            float4 v1 = h41[k];
            a0  += v0.x * whh[4*k]     + v0.z * whh[4*k + 2];
            a0b += v0.y * whh[4*k + 1] + v0.w * whh[4*k + 3];
            a1  += v1.x * whh[4*k]     + v1.z * whh[4*k + 2];
            a1b += v1.y * whh[4*k + 1] + v1.w * whh[4*k + 3];
        }
        gs0[t] = a0 + a0b;
        gs1[t] = a1 + a1b;
        __syncthreads();
        if (t < NH) {
            float gi = gs0[t], gf = gs0[t + NH], gg = gs0[t + 2 * NH], go = gs0[t + 3 * NH];
            cc = sigf(gf) * cc + sigf(gi) * tanhf(gg);
            hs0[t] = sigf(go) * tanhf(cc);
        } else if (t < 2 * NH) {
            const int d = t - NH;
            float gi = gs1[d], gf = gs1[d + NH], gg = gs1[d + 2 * NH], go = gs1[d + 3 * NH];
            cc = sigf(gf) * cc + sigf(gi) * tanhf(gg);
            hs1[d] = sigf(go) * tanhf(cc);
        }
        __syncthreads();
    }

    if (t < NH) {
        st[((b0 * 2 + dir) * 2 + 0) * NH + t] = hs0[t];
        st[((b0 * 2 + dir) * 2 + 1) * NH + t] = cc;
    } else if (t < 2 * NH) {
        const int d = t - NH;
        st[((b1 * 2 + dir) * 2 + 0) * NH + d] = hs1[d];
        st[((b1 * 2 + dir) * 2 + 1) * NH + d] = cc;
    }
}

// ---------------- decoder ----------------
// grid 256 (one WG per batch element); block 512; thread t owns gate row t of
// BOTH cells. f-cell W_hh fully in regs; b-cell W_hh split regs(56)/LDS(72).
__global__ __launch_bounds__(512, 1)
void dec_kernel(const float* __restrict__ x,
                const float* __restrict__ Wih_f, const float* __restrict__ Whh_f, const float* __restrict__ b_f,
                const float* __restrict__ Wih_b, const float* __restrict__ Whh_b, const float* __restrict__ b_b,
                const float* __restrict__ Wlin, const float* __restrict__ blin,
                const float* __restrict__ st, float* __restrict__ out)
{
    __shared__ float wbl[NG * WST];   // 512*73*4 = 149504 B
    __shared__ float hF[NH], hB[NH];
    __shared__ float inp[NI];
    __shared__ float gF[NG], gB[NG];
    __shared__ float prt[NG];

    const int b = blockIdx.x;
    const int t = threadIdx.x;

    // stage b-cell W_hh columns 56..127 into LDS (each thread its own row)
#pragma unroll
    for (int k = 0; k < WBL / 4; ++k) {
        float4 v = ((const float4*)(Whh_b + t * NH + WBR))[k];
        wbl[t * WST + 4*k]     = v.x;
        wbl[t * WST + 4*k + 1] = v.y;
        wbl[t * WST + 4*k + 2] = v.z;
        wbl[t * WST + 4*k + 3] = v.w;
    }

    float wf[NH];
#pragma unroll
    for (int k = 0; k < NH / 4; ++k) {
        float4 v = ((const float4*)(Whh_f + t * NH))[k];
        wf[4*k] = v.x; wf[4*k+1] = v.y; wf[4*k+2] = v.z; wf[4*k+3] = v.w;
    }
    float wb[WBR];
#pragma unroll
    for (int k = 0; k < WBR / 4; ++k) {
        float4 v = ((const float4*)(Whh_b + t * NH))[k];
        wb[4*k] = v.x; wb[4*k+1] = v.y; wb[4*k+2] = v.z; wb[4*k+3] = v.w;
    }
    float uf[NI], ub[NI];
#pragma unroll
    for (int k = 0; k < NI / 4; ++k) {
        float4 vf = ((const float4*)(Wih_f + t * NI))[k];
        float4 vb = ((const float4*)(Wih_b + t * NI))[k];
        uf[4*k] = vf.x; uf[4*k+1] = vf.y; uf[4*k+2] = vf.z; uf[4*k+3] = vf.w;
        ub[4*k] = vb.x; ub[4*k+1] = vb.y; ub[4*k+2] = vb.z; ub[4*k+3] = vb.w;
    }
    const float bf = b_f[t], bb = b_b[t];

    float cc = 0.0f;
    if (t < NH) {
        hF[t] = st[((b * 2 + 0) * 2 + 0) * NH + t];
        cc    = st[((b * 2 + 0) * 2 + 1) * NH + t];
    } else if (t < 2 * NH) {
        const int d = t - NH;
        hB[d] = st[((b * 2 + 1) * 2 + 0) * NH + d];
        cc    = st[((b * 2 + 1) * 2 + 1) * NH + d];
    }
    if (t < NI) inp[t] = x[b * TB * NI + (TB - 1) * NI + t];
    __syncthreads();

    for (int s = 0; s < PRED; ++s) {
        float aF = bf, aB = bb;
#pragma unroll
        for (int j = 0; j < NI; ++j) { float v = inp[j]; aF += v * uf[j]; aB += v * ub[j]; }
        const float4* h4F = (const float4*)hF;
#pragma unroll
        for (int k = 0; k < NH / 4; ++k) {
            float4 v = h4F[k];
            aF += v.x * wf[4*k] + v.y * wf[4*k+1] + v.z * wf[4*k+2] + v.w * wf[4*k+3];
        }
#pragma unroll
        for (int k = 0; k < WBR; ++k) aB += hB[k] * wb[k];
#pragma unroll
        for (int j = 0; j < WBL; ++j) aB += hB[WBR + j] * wbl[t * WST + j];
        gF[t] = aF;
        gB[t] = aB;
        __syncthreads();
        if (t < NH) {
            float gi = gF[t], gfr = gF[t + NH], gg = gF[t + 2 * NH], go = gF[t + 3 * NH];
            cc = sigf(gfr) * cc + sigf(gi) * tanhf(gg);
            hF[t] = sigf(go) * tanhf(cc);
        } else if (t < 2 * NH) {
            const int d = t - NH;
            float gi = gB[d], gfr = gB[d + NH], gg = gB[d + 2 * NH], go = gB[d + 3 * NH];
            cc = sigf(gfr) * cc + sigf(gi) * tanhf(gg);
            hB[d] = sigf(go) * tanhf(cc);
        }
        __syncthreads();
        // out = concat(hF,hB) @ Wlin^T + blin ; thread t -> (j = t>>5, ch = t&31)
        const int j = t >> 5, ch = t & 31;
        const float* src = (ch < 16) ? &hF[ch * 8] : &hB[ch * 8 - NH];
        const float* wl  = Wlin + j * (2 * NH) + ch * 8;
        float p = 0.0f;
#pragma unroll
        for (int q = 0; q < 8; ++q) p += src[q] * wl[q];
        prt[t] = p;
        __syncthreads();
        if (t < NI) {
            float o = blin[t];
#pragma unroll
            for (int c2 = 0; c2 < 32; ++c2) o += prt[t * 32 + c2];
            out[b * PRED * NI + s * NI + t] = o;
            inp[t] = o;
        }
        __syncthreads();
    }
}

extern "C" void kernel_launch(void* const* d_in, const int* in_sizes, int n_in,
                              void* d_out, int out_size, void* d_ws, size_t ws_size,
                              hipStream_t stream)
{
    const float* x      = (const float*)d_in[0];
    const float* eWih_f = (const float*)d_in[1];
    const float* eWhh_f = (const float*)d_in[2];
    const float* eb_f   = (const float*)d_in[3];
    const float* eWih_b = (const float*)d_in[4];
    const float* eWhh_b = (const float*)d_in[5];
    const float* eb_b   = (const float*)d_in[6];
    const float* dWih_f = (const float*)d_in[7];
    const float* dWhh_f = (const float*)d_in[8];
    const float* db_f   = (const float*)d_in[9];
    const float* dWih_b = (const float*)d_in[10];
    const float* dWhh_b = (const float*)d_in[11];
    const float* db_b   = (const float*)d_in[12];
    const float* Wlin   = (const float*)d_in[13];
    const float* blin   = (const float*)d_in[14];

    float* st = (float*)d_ws;  // NB*2*2*NH f32 encoder final states

    enc_kernel<<<256, 512, 0, stream>>>(x, eWih_f, eWhh_f, eb_f, eWih_b, eWhh_b, eb_b, st);
    dec_kernel<<<256, 512, 0, stream>>>(x, dWih_f, dWhh_f, db_f, dWih_b, dWhh_b, db_b,
                                        Wlin, blin, st, (float*)d_out);
}

// Round 3
// 1908.637 us; speedup vs baseline: 1.0020x; 1.0020x over previous
//
#include <hip/hip_runtime.h>
#include <math.h>

#define TB   720
#define NI   16
#define NH   128
#define NG   512   // 4*H
#define NB   256
#define PRED 96

// decoder: split of W_hh_b row: first WBR cols in regs, last WBL cols in LDS
#define WBR  56
#define WBL  72
#define WST  73    // LDS row stride (odd -> conflict-free)

__device__ __forceinline__ float sigf(float v) { return 1.0f / (1.0f + __expf(-v)); }

// ---------------- encoder ----------------
// grid 256 = (batch-pair) x (dir); block 512; thread t owns gate row t.
// waves_per_eu(2,2): pin 2 waves/SIMD -> 256-VGPR budget so whh[128] stays
// register-resident (R2: compiler capped at 124 VGPR and spilled -> L2-bound).
__global__ __attribute__((amdgpu_waves_per_eu(2, 2))) __launch_bounds__(512)
void enc_kernel(const float* __restrict__ x,
                const float* __restrict__ Wih_f, const float* __restrict__ Whh_f, const float* __restrict__ b_f,
                const float* __restrict__ Wih_b, const float* __restrict__ Whh_b, const float* __restrict__ b_b,
                float* __restrict__ st)   // st[b][dir][{h,c}][NH]
{
    __shared__ float xs0[TB * NI];
    __shared__ float xs1[TB * NI];
    __shared__ float hs0[NH];
    __shared__ float hs1[NH];
    __shared__ float gs0[NG];
    __shared__ float gs1[NG];

    const int wg  = blockIdx.x;
    const int dir = wg & 1;
    const int pb  = wg >> 1;
    const int b0  = 2 * pb, b1 = 2 * pb + 1;
    const int t   = threadIdx.x;

    const float* Wih = dir ? Wih_b : Wih_f;
    const float* Whh = dir ? Whh_b : Whh_f;
    const float* bv  = dir ? b_b   : b_f;

    // stage both x rows (T*I = 11520 f32 each)
    for (int i = t; i < TB * NI; i += 512) {
        xs0[i] = x[b0 * TB * NI + i];
        xs1[i] = x[b1 * TB * NI + i];
    }

    // weights -> registers
    float wih[NI];
#pragma unroll
    for (int k = 0; k < NI / 4; ++k) {
        float4 v = ((const float4*)(Wih + t * NI))[k];
        wih[4*k] = v.x; wih[4*k+1] = v.y; wih[4*k+2] = v.z; wih[4*k+3] = v.w;
    }
    float whh[NH];
#pragma unroll
    for (int k = 0; k < NH / 4; ++k) {
        float4 v = ((const float4*)(Whh + t * NH))[k];
        whh[4*k] = v.x; whh[4*k+1] = v.y; whh[4*k+2] = v.z; whh[4*k+3] = v.w;
    }
    const float bias = bv[t];

    if (t < NH) { hs0[t] = 0.0f; hs1[t] = 0.0f; }
    float cc = 0.0f;  // t<NH: c of b0 dim t ; NH<=t<2NH: c of b1 dim t-NH
    __syncthreads();

    for (int s = 0; s < TB; ++s) {
        const int tt = dir ? (TB - 1 - s) : s;
        const float* xp0 = &xs0[tt * NI];
        const float* xp1 = &xs1[tt * NI];
        float a0 = bias, a0b = 0.0f;
        float a1 = bias, a1b = 0.0f;
#pragma unroll
        for (int j = 0; j < NI; j += 2) {
            a0  += xp0[j]     * wih[j];
            a0b += xp0[j + 1] * wih[j + 1];
            a1  += xp1[j]     * wih[j];
            a1b += xp1[j + 1] * wih[j + 1];
        }
        const float4* h40 = (const float4*)hs0;
        const float4* h41 = (const float4*)hs1;
#pragma unroll
        for (int k = 0; k < NH / 4; ++k) {
            float4 v0 = h40[k];
            float4 v1 = h41[k];
            a0  += v0.x * whh[4*k]     + v0.z * whh[4*k + 2];
            a0b += v0.y * whh[4*k + 1] + v0.w * whh[4*k + 3];
            a1  += v1.x * whh[4*k]     + v1.z * whh[4*k + 2];
            a1b += v1.y * whh[4*k + 1] + v1.w * whh[4*k + 3];
        }
        gs0[t] = a0 + a0b;
        gs1[t] = a1 + a1b;
        __syncthreads();
        if (t < NH) {
            float gi = gs0[t], gf = gs0[t + NH], gg = gs0[t + 2 * NH], go = gs0[t + 3 * NH];
            cc = sigf(gf) * cc + sigf(gi) * tanhf(gg);
            hs0[t] = sigf(go) * tanhf(cc);
        } else if (t < 2 * NH) {
            const int d = t - NH;
            float gi = gs1[d], gf = gs1[d + NH], gg = gs1[d + 2 * NH], go = gs1[d + 3 * NH];
            cc = sigf(gf) * cc + sigf(gi) * tanhf(gg);
            hs1[d] = sigf(go) * tanhf(cc);
        }
        __syncthreads();
    }

    if (t < NH) {
        st[((b0 * 2 + dir) * 2 + 0) * NH + t] = hs0[t];
        st[((b0 * 2 + dir) * 2 + 1) * NH + t] = cc;
    } else if (t < 2 * NH) {
        const int d = t - NH;
        st[((b1 * 2 + dir) * 2 + 0) * NH + d] = hs1[d];
        st[((b1 * 2 + dir) * 2 + 1) * NH + d] = cc;
    }
}

// ---------------- decoder ----------------
// grid 256 (one WG per batch element); block 512; thread t owns gate row t of
// BOTH cells. f-cell W_hh fully in regs; b-cell W_hh split regs(56)/LDS(72).
__global__ __attribute__((amdgpu_waves_per_eu(2, 2))) __launch_bounds__(512)
void dec_kernel(const float* __restrict__ x,
                const float* __restrict__ Wih_f, const float* __restrict__ Whh_f, const float* __restrict__ b_f,
                const float* __restrict__ Wih_b, const float* __restrict__ Whh_b, const float* __restrict__ b_b,
                const float* __restrict__ Wlin, const float* __restrict__ blin,
                const float* __restrict__ st, float* __restrict__ out)
{
    __shared__ float wbl[NG * WST];   // 512*73*4 = 149504 B
    __shared__ float hF[NH], hB[NH];
    __shared__ float inp[NI];
    __shared__ float gF[NG], gB[NG];
    __shared__ float prt[NG];

    const int b = blockIdx.x;
    const int t = threadIdx.x;

    // stage b-cell W_hh columns 56..127 into LDS (each thread its own row)
#pragma unroll
    for (int k = 0; k < WBL / 4; ++k) {
        float4 v = ((const float4*)(Whh_b + t * NH + WBR))[k];
        wbl[t * WST + 4*k]     = v.x;
        wbl[t * WST + 4*k + 1] = v.y;
        wbl[t * WST + 4*k + 2] = v.z;
        wbl[t * WST + 4*k + 3] = v.w;
    }

    float wf[NH];
#pragma unroll
    for (int k = 0; k < NH / 4; ++k) {
        float4 v = ((const float4*)(Whh_f + t * NH))[k];
        wf[4*k] = v.x; wf[4*k+1] = v.y; wf[4*k+2] = v.z; wf[4*k+3] = v.w;
    }
    float wb[WBR];
#pragma unroll
    for (int k = 0; k < WBR / 4; ++k) {
        float4 v = ((const float4*)(Whh_b + t * NH))[k];
        wb[4*k] = v.x; wb[4*k+1] = v.y; wb[4*k+2] = v.z; wb[4*k+3] = v.w;
    }
    float uf[NI], ub[NI];
#pragma unroll
    for (int k = 0; k < NI / 4; ++k) {
        float4 vf = ((const float4*)(Wih_f + t * NI))[k];
        float4 vb = ((const float4*)(Wih_b + t * NI))[k];
        uf[4*k] = vf.x; uf[4*k+1] = vf.y; uf[4*k+2] = vf.z; uf[4*k+3] = vf.w;
        ub[4*k] = vb.x; ub[4*k+1] = vb.y; ub[4*k+2] = vb.z; ub[4*k+3] = vb.w;
    }
    const float bf = b_f[t], bb = b_b[t];

    float cc = 0.0f;
    if (t < NH) {
        hF[t] = st[((b * 2 + 0) * 2 + 0) * NH + t];
        cc    = st[((b * 2 + 0) * 2 + 1) * NH + t];
    } else if (t < 2 * NH) {
        const int d = t - NH;
        hB[d] = st[((b * 2 + 1) * 2 + 0) * NH + d];
        cc    = st[((b * 2 + 1) * 2 + 1) * NH + d];
    }
    if (t < NI) inp[t] = x[b * TB * NI + (TB - 1) * NI + t];
    __syncthreads();

    for (int s = 0; s < PRED; ++s) {
        float aF = bf, aB = bb;
#pragma unroll
        for (int j = 0; j < NI; ++j) { float v = inp[j]; aF += v * uf[j]; aB += v * ub[j]; }
        const float4* h4F = (const float4*)hF;
#pragma unroll
        for (int k = 0; k < NH / 4; ++k) {
            float4 v = h4F[k];
            aF += v.x * wf[4*k] + v.y * wf[4*k+1] + v.z * wf[4*k+2] + v.w * wf[4*k+3];
        }
#pragma unroll
        for (int k = 0; k < WBR; ++k) aB += hB[k] * wb[k];
#pragma unroll
        for (int j = 0; j < WBL; ++j) aB += hB[WBR + j] * wbl[t * WST + j];
        gF[t] = aF;
        gB[t] = aB;
        __syncthreads();
        if (t < NH) {
            float gi = gF[t], gfr = gF[t + NH], gg = gF[t + 2 * NH], go = gF[t + 3 * NH];
            cc = sigf(gfr) * cc + sigf(gi) * tanhf(gg);
            hF[t] = sigf(go) * tanhf(cc);
        } else if (t < 2 * NH) {
            const int d = t - NH;
            float gi = gB[d], gfr = gB[d + NH], gg = gB[d + 2 * NH], go = gB[d + 3 * NH];
            cc = sigf(gfr) * cc + sigf(gi) * tanhf(gg);
            hB[d] = sigf(go) * tanhf(cc);
        }
        __syncthreads();
        // out = concat(hF,hB) @ Wlin^T + blin ; thread t -> (j = t>>5, ch = t&31)
        const int j = t >> 5, ch = t & 31;
        const float* src = (ch < 16) ? &hF[ch * 8] : &hB[ch * 8 - NH];
        const float* wl  = Wlin + j * (2 * NH) + ch * 8;
        float p = 0.0f;
#pragma unroll
        for (int q = 0; q < 8; ++q) p += src[q] * wl[q];
        prt[t] = p;
        __syncthreads();
        if (t < NI) {
            float o = blin[t];
#pragma unroll
            for (int c2 = 0; c2 < 32; ++c2) o += prt[t * 32 + c2];
            out[b * PRED * NI + s * NI + t] = o;
            inp[t] = o;
        }
        __syncthreads();
    }
}

extern "C" void kernel_launch(void* const* d_in, const int* in_sizes, int n_in,
                              void* d_out, int out_size, void* d_ws, size_t ws_size,
                              hipStream_t stream)
{
    const float* x      = (const float*)d_in[0];
    const float* eWih_f = (const float*)d_in[1];
    const float* eWhh_f = (const float*)d_in[2];
    const float* eb_f   = (const float*)d_in[3];
    const float* eWih_b = (const float*)d_in[4];
    const float* eWhh_b = (const float*)d_in[5];
    const float* eb_b   = (const float*)d_in[6];
    const float* dWih_f = (const float*)d_in[7];
    const float* dWhh_f = (const float*)d_in[8];
    const float* db_f   = (const float*)d_in[9];
    const float* dWih_b = (const float*)d_in[10];
    const float* dWhh_b = (const float*)d_in[11];
    const float* db_b   = (const float*)d_in[12];
    const float* Wlin   = (const float*)d_in[13];
    const float* blin   = (const float*)d_in[14];

    float* st = (float*)d_ws;  // NB*2*2*NH f32 encoder final states

    enc_kernel<<<256, 512, 0, stream>>>(x, eWih_f, eWhh_f, eb_f, eWih_b, eWhh_b, eb_b, st);
    dec_kernel<<<256, 512, 0, stream>>>(x, dWih_f, dWhh_f, db_f, dWih_b, dWhh_b, db_b,
                                        Wlin, blin, st, (float*)d_out);
}